// Round 1
// baseline (441.303 us; speedup 1.0000x reference)
//
#include <hip/hip_runtime.h>
#include <math.h>

#define Bn 16
#define Ln 2048
#define Gn 8
#define Pn 8
#define Kn 64
#define CLAMP_V 15.0f

// ---------------------------------------------------------------------------
// init: copy x_native -> out coords, mask(int) -> out mask (as float 0/1),
// zero the drms accumulator workspace (harness poisons d_ws with 0xAA).
// ---------------------------------------------------------------------------
__global__ __launch_bounds__(256) void init_kernel(
    const float* __restrict__ xnat_in, const int* __restrict__ mask_in,
    float* __restrict__ out_x, float* __restrict__ out_m,
    float* __restrict__ drms) {
    int i = blockIdx.x * blockDim.x + threadIdx.x;
    if (i < Bn * Ln * 3) out_x[i] = xnat_in[i];
    if (i < Bn * Ln)     out_m[i] = (float)mask_in[i];
    if (i < Bn * Pn)     drms[i]  = 0.0f;
}

// ---------------------------------------------------------------------------
// drms accumulation for one group.
// grid = Bn * 16(l-chunks) * 2(k-chunks) = 512 blocks, 128 threads.
// Each thread owns one l, loops 32 k's, keeps 8 accumulators (one per p).
// (dp-dn)^2 = dp2 + dn2 - 2*sqrt(dp2*dn2)  -> 1 sqrt per (k,l,p) term,
// dp2 shared across the 8 p's.
// ---------------------------------------------------------------------------
__global__ __launch_bounds__(128) void drms_kernel(
    const float* __restrict__ xpred, const float* __restrict__ xnat,
    const int* __restrict__ ag,   // automorphs for this group: Pn*Kn ints
    float* __restrict__ drms) {
    const int tid = threadIdx.x;
    const int bid = blockIdx.x;
    const int b  = bid >> 5;          // 32 blocks per batch
    const int lc = (bid >> 1) & 15;   // l-chunk: 16 chunks of 128
    const int kc = bid & 1;           // k-chunk: 2 chunks of 32

    __shared__ int   s_a0[Kn];            // full base permutation (colmask test)
    __shared__ float s_ap[32][3];         // x_pred[b, a0[k]] for this k-chunk
    __shared__ float s_an[Pn][32][3];     // x_nat [b, a[p][k]] for this k-chunk

    if (tid < Kn) s_a0[tid] = ag[tid];
    if (tid < 32) {
        int col = ag[kc * 32 + tid];
        const float* p = xpred + ((size_t)b * Ln + col) * 3;
        s_ap[tid][0] = p[0]; s_ap[tid][1] = p[1]; s_ap[tid][2] = p[2];
    }
    for (int idx = tid; idx < Pn * 32; idx += 128) {
        int p  = idx >> 5;
        int kk = idx & 31;
        int col = ag[p * Kn + kc * 32 + kk];
        const float* q = xnat + ((size_t)b * Ln + col) * 3;
        s_an[p][kk][0] = q[0]; s_an[p][kk][1] = q[1]; s_an[p][kk][2] = q[2];
    }
    __syncthreads();

    const int l = lc * 128 + tid;
    const float* xpl = xpred + ((size_t)b * Ln + l) * 3;
    const float* xnl = xnat  + ((size_t)b * Ln + l) * 3;
    const float xpx = xpl[0], xpy = xpl[1], xpz = xpl[2];
    const float xnx = xnl[0], xny = xnl[1], xnz = xnl[2];

    bool masked = false;
    #pragma unroll
    for (int i = 0; i < Kn; i++) masked |= (s_a0[i] == l);

    float acc[Pn];
    #pragma unroll
    for (int p = 0; p < Pn; p++) acc[p] = 0.0f;

    if (!masked) {
        for (int kk = 0; kk < 32; kk++) {
            const float dx = s_ap[kk][0] - xpx;
            const float dy = s_ap[kk][1] - xpy;
            const float dz = s_ap[kk][2] - xpz;
            const float dp2 = dx*dx + dy*dy + dz*dz;
            #pragma unroll
            for (int p = 0; p < Pn; p++) {
                const float ex = s_an[p][kk][0] - xnx;
                const float ey = s_an[p][kk][1] - xny;
                const float ez = s_an[p][kk][2] - xnz;
                const float dn2 = ex*ex + ey*ey + ez*ez;
                const float s  = sqrtf(dp2 * dn2);     // = dp*dn
                const float t  = dp2 + dn2 - 2.0f * s; // = (dp-dn)^2
                acc[p] += fminf(t, CLAMP_V);
            }
        }
    }

    // wave-level reduction (wave = 64 lanes), one atomicAdd per wave per p
    #pragma unroll
    for (int p = 0; p < Pn; p++) {
        float v = acc[p];
        #pragma unroll
        for (int off = 32; off > 0; off >>= 1) v += __shfl_down(v, off, 64);
        if ((tid & 63) == 0) atomicAdd(&drms[b * Pn + p], v);
    }
}

// ---------------------------------------------------------------------------
// argmin over p, then gather a[bestj] rows and scatter onto a0 rows.
// One block per batch; gather completes before scatter (__syncthreads).
// Also re-zeroes this batch's drms slots for the next group.
// ---------------------------------------------------------------------------
__global__ __launch_bounds__(64) void select_kernel(
    float* __restrict__ xnat, float* __restrict__ nmask,
    const int* __restrict__ ag, float* __restrict__ drms) {
    const int b   = blockIdx.x;
    const int tid = threadIdx.x;  // 0..63 == k
    __shared__ int s_best;

    if (tid == 0) {
        float best = drms[b * Pn];
        int   bj   = 0;
        for (int p = 1; p < Pn; p++) {
            float v = drms[b * Pn + p];
            if (v < best) { best = v; bj = p; }  // strict < keeps first index (jnp.argmin)
        }
        s_best = bj;
    }
    __syncthreads();
    if (tid < Pn) drms[b * Pn + tid] = 0.0f;

    const int bj  = s_best;
    const int src = ag[bj * Kn + tid];  // a[bestj][k]
    const int dst = ag[tid];            // a0[k]

    const size_t sb = ((size_t)b * Ln + src) * 3;
    const float sx = xnat[sb + 0];
    const float sy = xnat[sb + 1];
    const float sz = xnat[sb + 2];
    const float sm = nmask[(size_t)b * Ln + src];
    __syncthreads();   // all gathers done before any scatter (same index set)

    const size_t db = ((size_t)b * Ln + dst) * 3;
    xnat[db + 0] = sx;
    xnat[db + 1] = sy;
    xnat[db + 2] = sz;
    nmask[(size_t)b * Ln + dst] = sm;
}

// ---------------------------------------------------------------------------
extern "C" void kernel_launch(void* const* d_in, const int* in_sizes, int n_in,
                              void* d_out, int out_size, void* d_ws, size_t ws_size,
                              hipStream_t stream) {
    const float* xpred   = (const float*)d_in[0];  // (B,L,3) f32
    const float* xnat_in = (const float*)d_in[1];  // (B,L,3) f32
    const int*   mask_in = (const int*)  d_in[2];  // (B,L) bool -> int32
    const int*   autom   = (const int*)  d_in[3];  // (G,P,K) int64 -> int32

    float* out_x = (float*)d_out;           // (B,L,3) flattened
    float* out_m = out_x + Bn * Ln * 3;     // (B,L) as float 0/1
    float* drms  = (float*)d_ws;            // Bn*Pn floats

    init_kernel<<<(Bn * Ln * 3 + 255) / 256, 256, 0, stream>>>(
        xnat_in, mask_in, out_x, out_m, drms);

    for (int g = 0; g < Gn; g++) {
        const int* ag = autom + g * Pn * Kn;
        drms_kernel<<<Bn * 32, 128, 0, stream>>>(xpred, out_x, ag, drms);
        select_kernel<<<Bn, 64, 0, stream>>>(out_x, out_m, ag, drms);
    }
}

// Round 2
// 211.893 us; speedup vs baseline: 2.0827x; 2.0827x over previous
//
#include <hip/hip_runtime.h>
#include <math.h>

#define Bn 16
#define Ln 2048
#define Gn 8
#define Pn 8
#define Kn 64
#define CLAMP_V 15.0f

#define LCHUNKS 64              // l-chunks per batch -> grid = Bn*64 = 1024 blocks
#define LPER (Ln / LCHUNKS)     // 32 l's per block
#define NWAVE 4                 // 256 threads/block
#define LPW (LPER / NWAVE)      // 8 l's per wave

// ---------------------------------------------------------------------------
// init: copy x_native -> out coords, mask(int) -> out mask (as float 0/1),
// zero the drms accumulator workspace (harness poisons d_ws with 0xAA).
// ---------------------------------------------------------------------------
__global__ __launch_bounds__(256) void init_kernel(
    const float* __restrict__ xnat_in, const int* __restrict__ mask_in,
    float* __restrict__ out_x, float* __restrict__ out_m,
    float* __restrict__ drms) {
    int i = blockIdx.x * blockDim.x + threadIdx.x;
    if (i < Bn * Ln * 3) out_x[i] = xnat_in[i];
    if (i < Bn * Ln)     out_m[i] = (float)mask_in[i];
    if (i < Bn * Pn)     drms[i]  = 0.0f;
}

// ---------------------------------------------------------------------------
// drms accumulation, lane = k layout.
// Each lane holds x_pred[b,a0[k]] and x_nat[b,a[p][k]] (p=0..7) in REGISTERS,
// loaded once per block. Inner loop over l: 6 wave-uniform loads + ~100 VALU
// covering all 64 k x 8 p. Column mask = one ballot + uniform skip.
// grid = Bn * LCHUNKS = 1024 blocks x 4 waves = 4 waves/SIMD.
// ---------------------------------------------------------------------------
__global__ __launch_bounds__(256) void drms_kernel(
    const float* __restrict__ xpred, const float* __restrict__ xnat,
    const int* __restrict__ ag,   // automorphs for this group: Pn*Kn ints
    float* __restrict__ drms) {
    const int lane = threadIdx.x & 63;
    const int wv   = threadIdx.x >> 6;
    const int b    = blockIdx.x >> 6;           // LCHUNKS = 64
    const int lc   = blockIdx.x & (LCHUNKS - 1);

    // lane k's fixed points, in registers for the whole kernel
    const int a0k = ag[lane];
    const float* pp = xpred + ((size_t)b * Ln + a0k) * 3;
    const float px = pp[0], py = pp[1], pz = pp[2];

    float nx[Pn], ny[Pn], nz[Pn];
    #pragma unroll
    for (int p = 0; p < Pn; p++) {
        const int col = ag[p * Kn + lane];
        const float* q = xnat + ((size_t)b * Ln + col) * 3;
        nx[p] = q[0]; ny[p] = q[1]; nz[p] = q[2];
    }

    float acc[Pn];
    #pragma unroll
    for (int p = 0; p < Pn; p++) acc[p] = 0.0f;

    const int l0 = lc * LPER + wv * LPW;
    #pragma unroll
    for (int i = 0; i < LPW; i++) {
        const int l  = l0 + i;
        // column masked out if l is in the base permutation (any lane matches)
        if (__ballot(a0k == l)) continue;   // uniform branch, rare (64/2048)

        const int lu = __builtin_amdgcn_readfirstlane(l);  // scalarize address
        const float* qp = xpred + ((size_t)b * Ln + lu) * 3;
        const float* qn = xnat  + ((size_t)b * Ln + lu) * 3;
        const float qx = qp[0], qy = qp[1], qz = qp[2];
        const float mx = qn[0], my = qn[1], mz = qn[2];

        const float dx = px - qx, dy = py - qy, dz = pz - qz;
        const float dp2 = dx * dx + dy * dy + dz * dz;

        #pragma unroll
        for (int p = 0; p < Pn; p++) {
            const float ex = nx[p] - mx, ey = ny[p] - my, ez = nz[p] - mz;
            const float dn2 = ex * ex + ey * ey + ez * ez;
            const float s   = sqrtf(dp2 * dn2);      // = dp*dn
            const float t   = dp2 + dn2 - 2.0f * s;  // = (dp-dn)^2
            acc[p] += fminf(t, CLAMP_V);
        }
    }

    // wave shuffle-reduce (sum over k), then block LDS reduce, 8 atomics/block
    __shared__ float s_part[NWAVE][Pn];
    #pragma unroll
    for (int p = 0; p < Pn; p++) {
        float v = acc[p];
        #pragma unroll
        for (int off = 32; off > 0; off >>= 1) v += __shfl_down(v, off, 64);
        if (lane == 0) s_part[wv][p] = v;
    }
    __syncthreads();
    if (threadIdx.x < Pn) {
        float v = s_part[0][threadIdx.x] + s_part[1][threadIdx.x]
                + s_part[2][threadIdx.x] + s_part[3][threadIdx.x];
        atomicAdd(&drms[b * Pn + threadIdx.x], v);
    }
}

// ---------------------------------------------------------------------------
// argmin over p, then gather a[bestj] rows and scatter onto a0 rows.
// One block per batch; gather completes before scatter (__syncthreads).
// Also re-zeroes this batch's drms slots for the next group.
// ---------------------------------------------------------------------------
__global__ __launch_bounds__(64) void select_kernel(
    float* __restrict__ xnat, float* __restrict__ nmask,
    const int* __restrict__ ag, float* __restrict__ drms) {
    const int b   = blockIdx.x;
    const int tid = threadIdx.x;  // 0..63 == k
    __shared__ int s_best;

    if (tid == 0) {
        float best = drms[b * Pn];
        int   bj   = 0;
        for (int p = 1; p < Pn; p++) {
            float v = drms[b * Pn + p];
            if (v < best) { best = v; bj = p; }  // strict < == jnp.argmin tie rule
        }
        s_best = bj;
    }
    __syncthreads();
    if (tid < Pn) drms[b * Pn + tid] = 0.0f;

    const int bj  = s_best;
    const int src = ag[bj * Kn + tid];  // a[bestj][k]
    const int dst = ag[tid];            // a0[k]

    const size_t sb = ((size_t)b * Ln + src) * 3;
    const float sx = xnat[sb + 0];
    const float sy = xnat[sb + 1];
    const float sz = xnat[sb + 2];
    const float sm = nmask[(size_t)b * Ln + src];
    __syncthreads();   // all gathers done before any scatter (same index set)

    const size_t db = ((size_t)b * Ln + dst) * 3;
    xnat[db + 0] = sx;
    xnat[db + 1] = sy;
    xnat[db + 2] = sz;
    nmask[(size_t)b * Ln + dst] = sm;
}

// ---------------------------------------------------------------------------
extern "C" void kernel_launch(void* const* d_in, const int* in_sizes, int n_in,
                              void* d_out, int out_size, void* d_ws, size_t ws_size,
                              hipStream_t stream) {
    const float* xpred   = (const float*)d_in[0];  // (B,L,3) f32
    const float* xnat_in = (const float*)d_in[1];  // (B,L,3) f32
    const int*   mask_in = (const int*)  d_in[2];  // (B,L) bool
    const int*   autom   = (const int*)  d_in[3];  // (G,P,K)

    float* out_x = (float*)d_out;           // (B,L,3) flattened
    float* out_m = out_x + Bn * Ln * 3;     // (B,L) as float 0/1
    float* drms  = (float*)d_ws;            // Bn*Pn floats

    init_kernel<<<(Bn * Ln * 3 + 255) / 256, 256, 0, stream>>>(
        xnat_in, mask_in, out_x, out_m, drms);

    for (int g = 0; g < Gn; g++) {
        const int* ag = autom + g * Pn * Kn;
        drms_kernel<<<Bn * LCHUNKS, 256, 0, stream>>>(xpred, out_x, ag, drms);
        select_kernel<<<Bn, 64, 0, stream>>>(out_x, out_m, ag, drms);
    }
}